// Round 3
// baseline (1201.558 us; speedup 1.0000x reference)
//
#include <hip/hip_runtime.h>

#define NN 1000000
#define NE 32000000
#define SCAN_B 256

// bucket decomposition: bucket = d >> 11, 2048 nodes per bucket.
// 489 blocks -> ~2 blocks/CU (1024 thr = 16 waves each) -> ~30/32 waves/CU.
// Round-2 lesson: passL1 is latency/occupancy-bound, NOT HBM-bound
// (FETCH 3.5x lower at identical dur). So: single sweep, more waves, MLP=8.
#define BK_SH 11
#define BK_SZ 2048
#define NB 489                       // ceil(NN / BK_SZ)
#define GAB 512                      // edge-chunk blocks for passes A and C
#define CHUNK 62500                  // 512 * 62500 = 32,000,000 exactly (div by 4)
#define NL (NB * GAB)                // hist length = 250368 (= 978 * 256)
#define NBS (NL / SCAN_B)            // 978 scan blocks (exact)

typedef int vi4 __attribute__((ext_vector_type(4)));

// ---- dtype detector: flag=1 if edge_index is int64, 0 if int32 ----
// int64 little-endian values < 2^31 have all-zero high (odd) words.
__global__ void detect_kernel(const int* __restrict__ ei, int* __restrict__ flag) {
    __shared__ int nz;
    if (threadIdx.x == 0) nz = 0;
    __syncthreads();
    int w = ei[2 * threadIdx.x + 1];
    if (w != 0) atomicAdd(&nz, 1);
    __syncthreads();
    if (threadIdx.x == 0) *flag = (nz == 0) ? 1 : 0;
}

// ---- pass A: per-block LDS histogram over buckets -> hist[b*GAB + g] ----
__global__ void passA_kernel(const int* __restrict__ ei, int* __restrict__ hist,
                             const int* __restrict__ flagp, int nE) {
    __shared__ int h[NB];
    int t = threadIdx.x;
    for (int b = t; b < NB; b += 512) h[b] = 0;
    __syncthreads();
    int shift = *flagp;
    int start = blockIdx.x * CHUNK;
    int end = min(start + CHUNK, nE);
    if (shift == 0) {
        const int* dstp = ei + nE;
        for (int i = start + (t << 2); i < end; i += 2048) {
            vi4 d = __builtin_nontemporal_load((const vi4*)(dstp + i));
            atomicAdd(&h[d.x >> BK_SH], 1);
            atomicAdd(&h[d.y >> BK_SH], 1);
            atomicAdd(&h[d.z >> BK_SH], 1);
            atomicAdd(&h[d.w >> BK_SH], 1);
        }
    } else {
        const int* dstp = ei + ((size_t)nE << 1);
        for (int i = start + t; i < end; i += 512) {
            int d = __builtin_nontemporal_load(dstp + ((size_t)i << 1));
            atomicAdd(&h[d >> BK_SH], 1);
        }
    }
    __syncthreads();
    for (int b = t; b < NB; b += 512)
        hist[(size_t)b * GAB + blockIdx.x] = h[b];
}

// ---- scan stage 1: per-block exclusive scan (in-place), block sums ----
__global__ void scan1_kernel(int* __restrict__ data, int* __restrict__ bsum, int n) {
    __shared__ int sm[SCAN_B];
    int t = threadIdx.x;
    int i = blockIdx.x * SCAN_B + t;
    int v = (i < n) ? data[i] : 0;
    sm[t] = v;
    __syncthreads();
    for (int o = 1; o < SCAN_B; o <<= 1) {
        int a = (t >= o) ? sm[t - o] : 0;
        __syncthreads();
        sm[t] += a;
        __syncthreads();
    }
    if (i < n) data[i] = sm[t] - v;
    if (t == SCAN_B - 1) bsum[blockIdx.x] = sm[t];
}

// ---- scan stage 2: exclusive scan of block sums (1 block, up to 4096) ----
__global__ void scan2_kernel(int* __restrict__ bsum, int nb) {
    __shared__ int sm[1024];
    int t = threadIdx.x;
    int base = t * 4;
    int v[4];
    int s = 0;
#pragma unroll
    for (int j = 0; j < 4; ++j) {
        v[j] = (base + j < nb) ? bsum[base + j] : 0;
        s += v[j];
    }
    sm[t] = s;
    __syncthreads();
    for (int o = 1; o < 1024; o <<= 1) {
        int a = (t >= o) ? sm[t - o] : 0;
        __syncthreads();
        sm[t] += a;
        __syncthreads();
    }
    int run = sm[t] - s;
#pragma unroll
    for (int j = 0; j < 4; ++j) {
        if (base + j < nb) bsum[base + j] = run;
        run += v[j];
    }
}

// ---- pass C: scatter packed edges into bucket-contiguous regions ----
// pairs[idx] = s | (d_local << 20)   (s < 2^20, d_local < 2^11)
__global__ void passC_kernel(const int* __restrict__ ei, const int* __restrict__ hist,
                             const int* __restrict__ bsum, unsigned int* __restrict__ pairs,
                             const int* __restrict__ flagp, int nE) {
    __shared__ int cur[NB];
    int t = threadIdx.x;
    for (int b = t; b < NB; b += 512) {
        int flat = b * GAB + blockIdx.x;
        cur[b] = hist[flat] + bsum[flat >> 8];
    }
    __syncthreads();
    int shift = *flagp;
    int start = blockIdx.x * CHUNK;
    int end = min(start + CHUNK, nE);
    if (shift == 0) {
        const int* srcp = ei;
        const int* dstp = ei + nE;
        for (int i = start + (t << 2); i < end; i += 2048) {
            vi4 s = __builtin_nontemporal_load((const vi4*)(srcp + i));
            vi4 d = __builtin_nontemporal_load((const vi4*)(dstp + i));
            int idx;
            idx = atomicAdd(&cur[d.x >> BK_SH], 1);
            pairs[idx] = (unsigned)s.x | ((unsigned)(d.x & (BK_SZ - 1)) << 20);
            idx = atomicAdd(&cur[d.y >> BK_SH], 1);
            pairs[idx] = (unsigned)s.y | ((unsigned)(d.y & (BK_SZ - 1)) << 20);
            idx = atomicAdd(&cur[d.z >> BK_SH], 1);
            pairs[idx] = (unsigned)s.z | ((unsigned)(d.z & (BK_SZ - 1)) << 20);
            idx = atomicAdd(&cur[d.w >> BK_SH], 1);
            pairs[idx] = (unsigned)s.w | ((unsigned)(d.w & (BK_SZ - 1)) << 20);
        }
    } else {
        for (int i = start + t; i < end; i += 512) {
            int s = __builtin_nontemporal_load(ei + ((size_t)i << 1));
            int d = __builtin_nontemporal_load(ei + ((size_t)nE << 1) + ((size_t)i << 1));
            int idx = atomicAdd(&cur[d >> BK_SH], 1);
            pairs[idx] = (unsigned)s | ((unsigned)(d & (BK_SZ - 1)) << 20);
        }
    }
}

__device__ __forceinline__ void bucket_range(const int* __restrict__ hist,
                                             const int* __restrict__ bsum,
                                             int b, int nE, int& base, int& endp) {
    int f0 = b * GAB;
    base = hist[f0] + bsum[f0 >> 8];
    if (b + 1 < NB) {
        int f1 = (b + 1) * GAB;
        endp = hist[f1] + bsum[f1 >> 8];
    } else {
        endp = nE;
    }
}

// ---- pass D0: per-bucket degree count -> dinv, xd = x * dinv ----
__global__ void passD0_kernel(const unsigned int* __restrict__ pairs,
                              const int* __restrict__ hist, const int* __restrict__ bsum,
                              const float2* __restrict__ x,
                              float* __restrict__ dinv, float2* __restrict__ xd,
                              int nE, int nN) {
    __shared__ int degl[BK_SZ];
    int t = threadIdx.x;
    int b = blockIdx.x;
    for (int j = t; j < BK_SZ; j += 1024) degl[j] = 0;
    __syncthreads();
    int base, endp;
    bucket_range(hist, bsum, b, nE, base, endp);
    for (int k = base + (t << 3); k < endp; k += 8192) {
        if (k + 8 <= endp) {
            unsigned int p[8];
#pragma unroll
            for (int j = 0; j < 8; ++j) p[j] = pairs[k + j];
#pragma unroll
            for (int j = 0; j < 8; ++j) atomicAdd(&degl[p[j] >> 20], 1);
        } else {
            for (int j = 0; k + j < endp; ++j) {
                unsigned int p = pairs[k + j];
                atomicAdd(&degl[p >> 20], 1);
            }
        }
    }
    __syncthreads();
    for (int j = t; j < BK_SZ; j += 1024) {
        int nid = (b << BK_SH) + j;
        if (nid < nN) {
            float di = rsqrtf((float)(degl[j] + 1));   // +1 self-loop
            dinv[nid] = di;
            float2 v = x[nid];
            xd[nid] = make_float2(v.x * di, v.y * di);
        }
    }
}

// ---- pass L1: per-bucket aggregate xd, fuse W1/b1/relu/W2 -> hd = h2*dinv ----
__global__ void passL1_kernel(const unsigned int* __restrict__ pairs,
                              const int* __restrict__ hist, const int* __restrict__ bsum,
                              const float* __restrict__ dinv, const float2* __restrict__ xd,
                              const float* __restrict__ W1, const float* __restrict__ b1,
                              const float* __restrict__ W2,
                              float* __restrict__ hd, int nE, int nN) {
    __shared__ float ax[BK_SZ];
    __shared__ float ay[BK_SZ];
    int t = threadIdx.x;
    int b = blockIdx.x;
    for (int j = t; j < BK_SZ; j += 1024) { ax[j] = 0.f; ay[j] = 0.f; }
    __syncthreads();
    int base, endp;
    bucket_range(hist, bsum, b, nE, base, endp);
    for (int k = base + (t << 3); k < endp; k += 8192) {
        if (k + 8 <= endp) {
            unsigned int p[8];
            float2 v[8];
#pragma unroll
            for (int j = 0; j < 8; ++j) p[j] = pairs[k + j];
#pragma unroll
            for (int j = 0; j < 8; ++j) v[j] = xd[p[j] & 0xFFFFF];
#pragma unroll
            for (int j = 0; j < 8; ++j) {
                int dl = p[j] >> 20;
                atomicAdd(&ax[dl], v[j].x);
                atomicAdd(&ay[dl], v[j].y);
            }
        } else {
            for (int j = 0; k + j < endp; ++j) {
                unsigned int p = pairs[k + j];
                float2 v = xd[p & 0xFFFFF];
                int dl = p >> 20;
                atomicAdd(&ax[dl], v.x);
                atomicAdd(&ay[dl], v.y);
            }
        }
    }
    __syncthreads();
    for (int j = t; j < BK_SZ; j += 1024) {
        int nid = (b << BK_SH) + j;
        if (nid < nN) {
            float dd = dinv[nid];
            float2 xs = xd[nid];
            float AX = (ax[j] + xs.x * dd) * dd;       // self-loop: xd*dd
            float AY = (ay[j] + xs.y * dd) * dd;
            float acc = 0.f;
#pragma unroll
            for (int c = 0; c < 8; ++c) {
                float h = fmaf(AX, W1[c], fmaf(AY, W1[8 + c], b1[c]));
                acc = fmaf(fmaxf(h, 0.f), W2[c], acc);
            }
            hd[nid] = acc * dd;                        // hd = h2 * dinv
        }
    }
}

// ---- pass L2: per-bucket aggregate hd, fuse sigmoid -> out ----
__global__ void passL2_kernel(const unsigned int* __restrict__ pairs,
                              const int* __restrict__ hist, const int* __restrict__ bsum,
                              const float* __restrict__ dinv, const float* __restrict__ hd,
                              const float* __restrict__ b2,
                              float* __restrict__ out, int nE, int nN) {
    __shared__ float ag[BK_SZ];
    int t = threadIdx.x;
    int b = blockIdx.x;
    for (int j = t; j < BK_SZ; j += 1024) ag[j] = 0.f;
    __syncthreads();
    int base, endp;
    bucket_range(hist, bsum, b, nE, base, endp);
    for (int k = base + (t << 3); k < endp; k += 8192) {
        if (k + 8 <= endp) {
            unsigned int p[8];
            float v[8];
#pragma unroll
            for (int j = 0; j < 8; ++j) p[j] = pairs[k + j];
#pragma unroll
            for (int j = 0; j < 8; ++j) v[j] = hd[p[j] & 0xFFFFF];
#pragma unroll
            for (int j = 0; j < 8; ++j) atomicAdd(&ag[p[j] >> 20], v[j]);
        } else {
            for (int j = 0; k + j < endp; ++j) {
                unsigned int p = pairs[k + j];
                atomicAdd(&ag[p >> 20], hd[p & 0xFFFFF]);
            }
        }
    }
    __syncthreads();
    for (int j = t; j < BK_SZ; j += 1024) {
        int nid = (b << BK_SH) + j;
        if (nid < nN) {
            float z = fmaf(dinv[nid], ag[j] + hd[nid], b2[0]);
            out[nid] = 1.f / (1.f + expf(-z));
        }
    }
}

// ================= fallback (small-workspace) atomic path =================

__global__ void deg_kernel(const int* __restrict__ ei, int* __restrict__ deg,
                           const int* __restrict__ flagp, int nE) {
    int i = blockIdx.x * blockDim.x + threadIdx.x;
    if (i >= nE) return;
    int shift = *flagp;
    int d = ei[((size_t)nE << shift) + ((size_t)i << shift)];
    atomicAdd(&deg[d], 1);
}

__global__ void prep_kernel(const int* __restrict__ deg, const float2* __restrict__ x,
                            float* __restrict__ dinv, float2* __restrict__ xd, int nN) {
    int i = blockIdx.x * blockDim.x + threadIdx.x;
    if (i >= nN) return;
    float di = rsqrtf((float)(deg[i] + 1));
    dinv[i] = di;
    float2 v = x[i];
    xd[i] = make_float2(v.x * di, v.y * di);
}

__device__ __forceinline__ void load_edge(const int* __restrict__ ei, int shift,
                                          int nE, int i, int& s, int& d) {
    s = ei[(size_t)i << shift];
    d = ei[((size_t)nE << shift) + ((size_t)i << shift)];
}

__global__ void l1a_kernel(const int* __restrict__ ei, const float2* __restrict__ xd,
                           float* __restrict__ agg, const int* __restrict__ flagp, int nE) {
    int i = blockIdx.x * blockDim.x + threadIdx.x;
    if (i >= nE) return;
    int shift = *flagp;
    int s, d;
    load_edge(ei, shift, nE, i, s, d);
    float2 v = xd[s];
    unsafeAtomicAdd(&agg[(size_t)d * 2], v.x);
    unsafeAtomicAdd(&agg[(size_t)d * 2 + 1], v.y);
}

__global__ void h2f_kernel(const float2* __restrict__ agg, const float2* __restrict__ xd,
                           const float* __restrict__ dinv, const float* __restrict__ W1,
                           const float* __restrict__ b1, const float* __restrict__ W2,
                           float* __restrict__ hd, int nN) {
    int d = blockIdx.x * blockDim.x + threadIdx.x;
    if (d >= nN) return;
    float dd = dinv[d];
    float2 a = agg[d];
    float2 xs = xd[d];
    float ax = (a.x + xs.x * dd) * dd;
    float ay = (a.y + xs.y * dd) * dd;
    float acc = 0.f;
#pragma unroll
    for (int j = 0; j < 8; ++j) {
        float h = fmaf(ax, W1[j], fmaf(ay, W1[8 + j], b1[j]));
        acc = fmaf(fmaxf(h, 0.f), W2[j], acc);
    }
    hd[d] = acc * dd;
}

__global__ void l2a_kernel(const int* __restrict__ ei, const float* __restrict__ hd,
                           float* __restrict__ out2, const int* __restrict__ flagp, int nE) {
    int i = blockIdx.x * blockDim.x + threadIdx.x;
    if (i >= nE) return;
    int shift = *flagp;
    int s, d;
    load_edge(ei, shift, nE, i, s, d);
    unsafeAtomicAdd(&out2[d], hd[s]);
}

__global__ void finf_kernel(const float* __restrict__ out2, const float* __restrict__ hd,
                            const float* __restrict__ dinv, const float* __restrict__ b2,
                            float* __restrict__ out, int nN) {
    int d = blockIdx.x * blockDim.x + threadIdx.x;
    if (d >= nN) return;
    float z = fmaf(dinv[d], out2[d] + hd[d], b2[0]);
    out[d] = 1.f / (1.f + expf(-z));
}

extern "C" void kernel_launch(void* const* d_in, const int* in_sizes, int n_in,
                              void* d_out, int out_size, void* d_ws, size_t ws_size,
                              hipStream_t stream) {
    const float* x  = (const float*)d_in[0];
    const int*   ei = (const int*)d_in[1];
    const float* W1 = (const float*)d_in[2];
    const float* b1 = (const float*)d_in[3];
    const float* W2 = (const float*)d_in[4];
    const float* b2 = (const float*)d_in[5];
    float* out = (float*)d_out;

    const int nE = NE, nN = NN;
    const int bs = 256;
    char* ws = (char*)d_ws;
    const size_t MiB = 1 << 20;

    // bucket-path layout: hist@0 (0.96MiB)  bsum@1MiB  flag@1MiB+64K
    //                     dinv@2MiB  xd@6MiB  hd@14MiB  pairs@18MiB (128MB)
    const size_t csr_need = 18 * MiB + (size_t)nE * 4;

    if (ws_size >= csr_need) {
        int*          hist  = (int*)ws;
        int*          bsum  = (int*)(ws + 1 * MiB);
        int*          flag  = (int*)(ws + 1 * MiB + 65536);
        float*        dinv  = (float*)(ws + 2 * MiB);
        float2*       xd    = (float2*)(ws + 6 * MiB);
        float*        hd    = (float*)(ws + 14 * MiB);
        unsigned int* pairs = (unsigned int*)(ws + 18 * MiB);

        detect_kernel<<<1, 256, 0, stream>>>(ei, flag);
        passA_kernel<<<GAB, 512, 0, stream>>>(ei, hist, flag, nE);
        scan1_kernel<<<NBS, SCAN_B, 0, stream>>>(hist, bsum, NL);
        scan2_kernel<<<1, 1024, 0, stream>>>(bsum, NBS);
        passC_kernel<<<GAB, 512, 0, stream>>>(ei, hist, bsum, pairs, flag, nE);
        passD0_kernel<<<NB, 1024, 0, stream>>>(pairs, hist, bsum, (const float2*)x,
                                               dinv, xd, nE, nN);
        passL1_kernel<<<NB, 1024, 0, stream>>>(pairs, hist, bsum, dinv, xd,
                                               W1, b1, W2, hd, nE, nN);
        passL2_kernel<<<NB, 1024, 0, stream>>>(pairs, hist, bsum, dinv, hd,
                                               b2, out, nE, nN);
    } else {
        // fallback layout: deg@0  agg@4..12  out2@12  dinv@16  xd@20..28  hd@28  flag@32MiB
        int*    deg  = (int*)ws;
        float*  agg  = (float*)(ws + 4 * MiB);
        float*  out2 = (float*)(ws + 12 * MiB);
        float*  dinv = (float*)(ws + 16 * MiB);
        float2* xd   = (float2*)(ws + 20 * MiB);
        float*  hd   = (float*)(ws + 28 * MiB);
        int*    flag = (int*)(ws + 32 * MiB);

        hipMemsetAsync(ws, 0, 16 * MiB, stream);

        detect_kernel<<<1, 256, 0, stream>>>(ei, flag);
        deg_kernel<<<(nE + bs - 1) / bs, bs, 0, stream>>>(ei, deg, flag, nE);
        prep_kernel<<<(nN + bs - 1) / bs, bs, 0, stream>>>(deg, (const float2*)x, dinv, xd, nN);
        l1a_kernel<<<(nE + bs - 1) / bs, bs, 0, stream>>>(ei, xd, agg, flag, nE);
        h2f_kernel<<<(nN + bs - 1) / bs, bs, 0, stream>>>((const float2*)agg, xd, dinv,
                                                          W1, b1, W2, hd, nN);
        l2a_kernel<<<(nE + bs - 1) / bs, bs, 0, stream>>>(ei, hd, out2, flag, nE);
        finf_kernel<<<(nN + bs - 1) / bs, bs, 0, stream>>>(out2, hd, dinv, b2, out, nN);
    }
}

// Round 4
// 1199.714 us; speedup vs baseline: 1.0015x; 1.0015x over previous
//
#include <hip/hip_runtime.h>

#define NN 1000000
#define NE 32000000
#define SCAN_B 256

// bucket decomposition: bucket = d >> 11, 2048 nodes per bucket.
// Cost model (validated rounds 0-3): per-bucket sweeps are bound by a per-CU
// cache-line access pipe (~4.5 cyc/line/CU), NOT HBM BW, NOT occupancy, NOT MLP.
// => minimize distinct-line touches per edge. pairs loads are made fully
// contiguous 16B vector loads (0.0625 lines/edge vs 0.5 scalar).
#define BK_SH 11
#define BK_SZ 2048
#define NB 489                       // ceil(NN / BK_SZ)
#define GAB 512                      // edge-chunk blocks for passes A and C
#define CHUNK 62500                  // 512 * 62500 = 32,000,000 exactly (div by 4)
#define NL (NB * GAB)                // hist length = 250368 (= 978 * 256)
#define NBS (NL / SCAN_B)            // 978 scan blocks (exact)

typedef int vi4 __attribute__((ext_vector_type(4)));

// ---- dtype detector: flag=1 if edge_index is int64, 0 if int32 ----
// int64 little-endian values < 2^31 have all-zero high (odd) words.
__global__ void detect_kernel(const int* __restrict__ ei, int* __restrict__ flag) {
    __shared__ int nz;
    if (threadIdx.x == 0) nz = 0;
    __syncthreads();
    int w = ei[2 * threadIdx.x + 1];
    if (w != 0) atomicAdd(&nz, 1);
    __syncthreads();
    if (threadIdx.x == 0) *flag = (nz == 0) ? 1 : 0;
}

// ---- pass A: per-block LDS histogram over buckets -> hist[b*GAB + g] ----
__global__ void passA_kernel(const int* __restrict__ ei, int* __restrict__ hist,
                             const int* __restrict__ flagp, int nE) {
    __shared__ int h[NB];
    int t = threadIdx.x;
    for (int b = t; b < NB; b += 512) h[b] = 0;
    __syncthreads();
    int shift = *flagp;
    int start = blockIdx.x * CHUNK;
    int end = min(start + CHUNK, nE);
    if (shift == 0) {
        const int* dstp = ei + nE;
        for (int i = start + (t << 2); i < end; i += 2048) {
            vi4 d = __builtin_nontemporal_load((const vi4*)(dstp + i));
            atomicAdd(&h[d.x >> BK_SH], 1);
            atomicAdd(&h[d.y >> BK_SH], 1);
            atomicAdd(&h[d.z >> BK_SH], 1);
            atomicAdd(&h[d.w >> BK_SH], 1);
        }
    } else {
        const int* dstp = ei + ((size_t)nE << 1);
        for (int i = start + t; i < end; i += 512) {
            int d = __builtin_nontemporal_load(dstp + ((size_t)i << 1));
            atomicAdd(&h[d >> BK_SH], 1);
        }
    }
    __syncthreads();
    for (int b = t; b < NB; b += 512)
        hist[(size_t)b * GAB + blockIdx.x] = h[b];
}

// ---- scan stage 1: per-block exclusive scan (in-place), block sums ----
__global__ void scan1_kernel(int* __restrict__ data, int* __restrict__ bsum, int n) {
    __shared__ int sm[SCAN_B];
    int t = threadIdx.x;
    int i = blockIdx.x * SCAN_B + t;
    int v = (i < n) ? data[i] : 0;
    sm[t] = v;
    __syncthreads();
    for (int o = 1; o < SCAN_B; o <<= 1) {
        int a = (t >= o) ? sm[t - o] : 0;
        __syncthreads();
        sm[t] += a;
        __syncthreads();
    }
    if (i < n) data[i] = sm[t] - v;
    if (t == SCAN_B - 1) bsum[blockIdx.x] = sm[t];
}

// ---- scan stage 2: exclusive scan of block sums (1 block, up to 4096) ----
__global__ void scan2_kernel(int* __restrict__ bsum, int nb) {
    __shared__ int sm[1024];
    int t = threadIdx.x;
    int base = t * 4;
    int v[4];
    int s = 0;
#pragma unroll
    for (int j = 0; j < 4; ++j) {
        v[j] = (base + j < nb) ? bsum[base + j] : 0;
        s += v[j];
    }
    sm[t] = s;
    __syncthreads();
    for (int o = 1; o < 1024; o <<= 1) {
        int a = (t >= o) ? sm[t - o] : 0;
        __syncthreads();
        sm[t] += a;
        __syncthreads();
    }
    int run = sm[t] - s;
#pragma unroll
    for (int j = 0; j < 4; ++j) {
        if (base + j < nb) bsum[base + j] = run;
        run += v[j];
    }
}

// ---- pass C: scatter packed edges into bucket-contiguous regions ----
// pairs[idx] = s | (d_local << 20)   (s < 2^20, d_local < 2^11)
__global__ void passC_kernel(const int* __restrict__ ei, const int* __restrict__ hist,
                             const int* __restrict__ bsum, unsigned int* __restrict__ pairs,
                             const int* __restrict__ flagp, int nE) {
    __shared__ int cur[NB];
    int t = threadIdx.x;
    for (int b = t; b < NB; b += 512) {
        int flat = b * GAB + blockIdx.x;
        cur[b] = hist[flat] + bsum[flat >> 8];
    }
    __syncthreads();
    int shift = *flagp;
    int start = blockIdx.x * CHUNK;
    int end = min(start + CHUNK, nE);
    if (shift == 0) {
        const int* srcp = ei;
        const int* dstp = ei + nE;
        for (int i = start + (t << 2); i < end; i += 2048) {
            vi4 s = __builtin_nontemporal_load((const vi4*)(srcp + i));
            vi4 d = __builtin_nontemporal_load((const vi4*)(dstp + i));
            int idx;
            idx = atomicAdd(&cur[d.x >> BK_SH], 1);
            pairs[idx] = (unsigned)s.x | ((unsigned)(d.x & (BK_SZ - 1)) << 20);
            idx = atomicAdd(&cur[d.y >> BK_SH], 1);
            pairs[idx] = (unsigned)s.y | ((unsigned)(d.y & (BK_SZ - 1)) << 20);
            idx = atomicAdd(&cur[d.z >> BK_SH], 1);
            pairs[idx] = (unsigned)s.z | ((unsigned)(d.z & (BK_SZ - 1)) << 20);
            idx = atomicAdd(&cur[d.w >> BK_SH], 1);
            pairs[idx] = (unsigned)s.w | ((unsigned)(d.w & (BK_SZ - 1)) << 20);
        }
    } else {
        for (int i = start + t; i < end; i += 512) {
            int s = __builtin_nontemporal_load(ei + ((size_t)i << 1));
            int d = __builtin_nontemporal_load(ei + ((size_t)nE << 1) + ((size_t)i << 1));
            int idx = atomicAdd(&cur[d >> BK_SH], 1);
            pairs[idx] = (unsigned)s | ((unsigned)(d & (BK_SZ - 1)) << 20);
        }
    }
}

__device__ __forceinline__ void bucket_range(const int* __restrict__ hist,
                                             const int* __restrict__ bsum,
                                             int b, int nE, int& base, int& endp) {
    int f0 = b * GAB;
    base = hist[f0] + bsum[f0 >> 8];
    if (b + 1 < NB) {
        int f1 = (b + 1) * GAB;
        endp = hist[f1] + bsum[f1 >> 8];
    } else {
        endp = nE;
    }
}

// aligned sweep bounds: [base, abase) scalar prologue (<=3), [abase, rend) in
// aligned vi4 quads, [rend, endp) scalar tail (<=3).
__device__ __forceinline__ void aligned_range(int base, int endp, int& abase, int& rend) {
    abase = (base + 3) & ~3;
    if (abase > endp) abase = endp;
    rend = abase + ((endp - abase) & ~3);
}

// ---- pass D0: per-bucket degree count -> dinv, xd = x * dinv ----
__global__ void passD0_kernel(const unsigned int* __restrict__ pairs,
                              const int* __restrict__ hist, const int* __restrict__ bsum,
                              const float2* __restrict__ x,
                              float* __restrict__ dinv, float2* __restrict__ xd,
                              int nE, int nN) {
    __shared__ int degl[BK_SZ];
    int t = threadIdx.x;
    int b = blockIdx.x;
    for (int j = t; j < BK_SZ; j += 1024) degl[j] = 0;
    __syncthreads();
    int base, endp, abase, rend;
    bucket_range(hist, bsum, b, nE, base, endp);
    aligned_range(base, endp, abase, rend);
    // prologue + tail (scalar, <=3 each)
    {
        int k = base + t;
        if (k < abase) atomicAdd(&degl[pairs[k] >> 20], 1);
        int k2 = rend + t;
        if (k2 < endp) atomicAdd(&degl[pairs[k2] >> 20], 1);
    }
    for (int k = abase + (t << 2); k + 4 <= rend; k += 4096) {
        vi4 q = *(const vi4*)(pairs + k);
        atomicAdd(&degl[(unsigned)q.x >> 20], 1);
        atomicAdd(&degl[(unsigned)q.y >> 20], 1);
        atomicAdd(&degl[(unsigned)q.z >> 20], 1);
        atomicAdd(&degl[(unsigned)q.w >> 20], 1);
    }
    __syncthreads();
    for (int j = t; j < BK_SZ; j += 1024) {
        int nid = (b << BK_SH) + j;
        if (nid < nN) {
            float di = rsqrtf((float)(degl[j] + 1));   // +1 self-loop
            dinv[nid] = di;
            float2 v = x[nid];
            xd[nid] = make_float2(v.x * di, v.y * di);
        }
    }
}

// ---- pass L1: per-bucket aggregate xd, fuse W1/b1/relu/W2 -> hd = h2*dinv ----
__global__ void passL1_kernel(const unsigned int* __restrict__ pairs,
                              const int* __restrict__ hist, const int* __restrict__ bsum,
                              const float* __restrict__ dinv, const float2* __restrict__ xd,
                              const float* __restrict__ W1, const float* __restrict__ b1,
                              const float* __restrict__ W2,
                              float* __restrict__ hd, int nE, int nN) {
    __shared__ float ax[BK_SZ];
    __shared__ float ay[BK_SZ];
    int t = threadIdx.x;
    int b = blockIdx.x;
    for (int j = t; j < BK_SZ; j += 1024) { ax[j] = 0.f; ay[j] = 0.f; }
    __syncthreads();
    int base, endp, abase, rend;
    bucket_range(hist, bsum, b, nE, base, endp);
    aligned_range(base, endp, abase, rend);
    {
        int k = base + t;
        if (k < abase) {
            unsigned int p = pairs[k];
            float2 v = xd[p & 0xFFFFF];
            atomicAdd(&ax[p >> 20], v.x);
            atomicAdd(&ay[p >> 20], v.y);
        }
        int k2 = rend + t;
        if (k2 < endp) {
            unsigned int p = pairs[k2];
            float2 v = xd[p & 0xFFFFF];
            atomicAdd(&ax[p >> 20], v.x);
            atomicAdd(&ay[p >> 20], v.y);
        }
    }
    for (int k = abase + (t << 2); k + 4 <= rend; k += 4096) {
        vi4 q = *(const vi4*)(pairs + k);
        unsigned int p[4] = {(unsigned)q.x, (unsigned)q.y, (unsigned)q.z, (unsigned)q.w};
        float2 v[4];
#pragma unroll
        for (int j = 0; j < 4; ++j) v[j] = xd[p[j] & 0xFFFFF];
#pragma unroll
        for (int j = 0; j < 4; ++j) {
            int dl = p[j] >> 20;
            atomicAdd(&ax[dl], v[j].x);
            atomicAdd(&ay[dl], v[j].y);
        }
    }
    __syncthreads();
    for (int j = t; j < BK_SZ; j += 1024) {
        int nid = (b << BK_SH) + j;
        if (nid < nN) {
            float dd = dinv[nid];
            float2 xs = xd[nid];
            float AX = (ax[j] + xs.x * dd) * dd;       // self-loop: xd*dd
            float AY = (ay[j] + xs.y * dd) * dd;
            float acc = 0.f;
#pragma unroll
            for (int c = 0; c < 8; ++c) {
                float h = fmaf(AX, W1[c], fmaf(AY, W1[8 + c], b1[c]));
                acc = fmaf(fmaxf(h, 0.f), W2[c], acc);
            }
            hd[nid] = acc * dd;                        // hd = h2 * dinv
        }
    }
}

// ---- pass L2: per-bucket aggregate hd, fuse sigmoid -> out ----
__global__ void passL2_kernel(const unsigned int* __restrict__ pairs,
                              const int* __restrict__ hist, const int* __restrict__ bsum,
                              const float* __restrict__ dinv, const float* __restrict__ hd,
                              const float* __restrict__ b2,
                              float* __restrict__ out, int nE, int nN) {
    __shared__ float ag[BK_SZ];
    int t = threadIdx.x;
    int b = blockIdx.x;
    for (int j = t; j < BK_SZ; j += 1024) ag[j] = 0.f;
    __syncthreads();
    int base, endp, abase, rend;
    bucket_range(hist, bsum, b, nE, base, endp);
    aligned_range(base, endp, abase, rend);
    {
        int k = base + t;
        if (k < abase) {
            unsigned int p = pairs[k];
            atomicAdd(&ag[p >> 20], hd[p & 0xFFFFF]);
        }
        int k2 = rend + t;
        if (k2 < endp) {
            unsigned int p = pairs[k2];
            atomicAdd(&ag[p >> 20], hd[p & 0xFFFFF]);
        }
    }
    for (int k = abase + (t << 2); k + 4 <= rend; k += 4096) {
        vi4 q = *(const vi4*)(pairs + k);
        unsigned int p[4] = {(unsigned)q.x, (unsigned)q.y, (unsigned)q.z, (unsigned)q.w};
        float v[4];
#pragma unroll
        for (int j = 0; j < 4; ++j) v[j] = hd[p[j] & 0xFFFFF];
#pragma unroll
        for (int j = 0; j < 4; ++j) atomicAdd(&ag[p[j] >> 20], v[j]);
    }
    __syncthreads();
    for (int j = t; j < BK_SZ; j += 1024) {
        int nid = (b << BK_SH) + j;
        if (nid < nN) {
            float z = fmaf(dinv[nid], ag[j] + hd[nid], b2[0]);
            out[nid] = 1.f / (1.f + expf(-z));
        }
    }
}

// ================= fallback (small-workspace) atomic path =================

__global__ void deg_kernel(const int* __restrict__ ei, int* __restrict__ deg,
                           const int* __restrict__ flagp, int nE) {
    int i = blockIdx.x * blockDim.x + threadIdx.x;
    if (i >= nE) return;
    int shift = *flagp;
    int d = ei[((size_t)nE << shift) + ((size_t)i << shift)];
    atomicAdd(&deg[d], 1);
}

__global__ void prep_kernel(const int* __restrict__ deg, const float2* __restrict__ x,
                            float* __restrict__ dinv, float2* __restrict__ xd, int nN) {
    int i = blockIdx.x * blockDim.x + threadIdx.x;
    if (i >= nN) return;
    float di = rsqrtf((float)(deg[i] + 1));
    dinv[i] = di;
    float2 v = x[i];
    xd[i] = make_float2(v.x * di, v.y * di);
}

__device__ __forceinline__ void load_edge(const int* __restrict__ ei, int shift,
                                          int nE, int i, int& s, int& d) {
    s = ei[(size_t)i << shift];
    d = ei[((size_t)nE << shift) + ((size_t)i << shift)];
}

__global__ void l1a_kernel(const int* __restrict__ ei, const float2* __restrict__ xd,
                           float* __restrict__ agg, const int* __restrict__ flagp, int nE) {
    int i = blockIdx.x * blockDim.x + threadIdx.x;
    if (i >= nE) return;
    int shift = *flagp;
    int s, d;
    load_edge(ei, shift, nE, i, s, d);
    float2 v = xd[s];
    unsafeAtomicAdd(&agg[(size_t)d * 2], v.x);
    unsafeAtomicAdd(&agg[(size_t)d * 2 + 1], v.y);
}

__global__ void h2f_kernel(const float2* __restrict__ agg, const float2* __restrict__ xd,
                           const float* __restrict__ dinv, const float* __restrict__ W1,
                           const float* __restrict__ b1, const float* __restrict__ W2,
                           float* __restrict__ hd, int nN) {
    int d = blockIdx.x * blockDim.x + threadIdx.x;
    if (d >= nN) return;
    float dd = dinv[d];
    float2 a = agg[d];
    float2 xs = xd[d];
    float ax = (a.x + xs.x * dd) * dd;
    float ay = (a.y + xs.y * dd) * dd;
    float acc = 0.f;
#pragma unroll
    for (int j = 0; j < 8; ++j) {
        float h = fmaf(ax, W1[j], fmaf(ay, W1[8 + j], b1[j]));
        acc = fmaf(fmaxf(h, 0.f), W2[j], acc);
    }
    hd[d] = acc * dd;
}

__global__ void l2a_kernel(const int* __restrict__ ei, const float* __restrict__ hd,
                           float* __restrict__ out2, const int* __restrict__ flagp, int nE) {
    int i = blockIdx.x * blockDim.x + threadIdx.x;
    if (i >= nE) return;
    int shift = *flagp;
    int s, d;
    load_edge(ei, shift, nE, i, s, d);
    unsafeAtomicAdd(&out2[d], hd[s]);
}

__global__ void finf_kernel(const float* __restrict__ out2, const float* __restrict__ hd,
                            const float* __restrict__ dinv, const float* __restrict__ b2,
                            float* __restrict__ out, int nN) {
    int d = blockIdx.x * blockDim.x + threadIdx.x;
    if (d >= nN) return;
    float z = fmaf(dinv[d], out2[d] + hd[d], b2[0]);
    out[d] = 1.f / (1.f + expf(-z));
}

extern "C" void kernel_launch(void* const* d_in, const int* in_sizes, int n_in,
                              void* d_out, int out_size, void* d_ws, size_t ws_size,
                              hipStream_t stream) {
    const float* x  = (const float*)d_in[0];
    const int*   ei = (const int*)d_in[1];
    const float* W1 = (const float*)d_in[2];
    const float* b1 = (const float*)d_in[3];
    const float* W2 = (const float*)d_in[4];
    const float* b2 = (const float*)d_in[5];
    float* out = (float*)d_out;

    const int nE = NE, nN = NN;
    const int bs = 256;
    char* ws = (char*)d_ws;
    const size_t MiB = 1 << 20;

    // bucket-path layout: hist@0 (0.96MiB)  bsum@1MiB  flag@1MiB+64K
    //                     dinv@2MiB  xd@6MiB  hd@14MiB  pairs@18MiB (128MB)
    const size_t csr_need = 18 * MiB + (size_t)nE * 4;

    if (ws_size >= csr_need) {
        int*          hist  = (int*)ws;
        int*          bsum  = (int*)(ws + 1 * MiB);
        int*          flag  = (int*)(ws + 1 * MiB + 65536);
        float*        dinv  = (float*)(ws + 2 * MiB);
        float2*       xd    = (float2*)(ws + 6 * MiB);
        float*        hd    = (float*)(ws + 14 * MiB);
        unsigned int* pairs = (unsigned int*)(ws + 18 * MiB);

        detect_kernel<<<1, 256, 0, stream>>>(ei, flag);
        passA_kernel<<<GAB, 512, 0, stream>>>(ei, hist, flag, nE);
        scan1_kernel<<<NBS, SCAN_B, 0, stream>>>(hist, bsum, NL);
        scan2_kernel<<<1, 1024, 0, stream>>>(bsum, NBS);
        passC_kernel<<<GAB, 512, 0, stream>>>(ei, hist, bsum, pairs, flag, nE);
        passD0_kernel<<<NB, 1024, 0, stream>>>(pairs, hist, bsum, (const float2*)x,
                                               dinv, xd, nE, nN);
        passL1_kernel<<<NB, 1024, 0, stream>>>(pairs, hist, bsum, dinv, xd,
                                               W1, b1, W2, hd, nE, nN);
        passL2_kernel<<<NB, 1024, 0, stream>>>(pairs, hist, bsum, dinv, hd,
                                               b2, out, nE, nN);
    } else {
        // fallback layout: deg@0  agg@4..12  out2@12  dinv@16  xd@20..28  hd@28  flag@32MiB
        int*    deg  = (int*)ws;
        float*  agg  = (float*)(ws + 4 * MiB);
        float*  out2 = (float*)(ws + 12 * MiB);
        float*  dinv = (float*)(ws + 16 * MiB);
        float2* xd   = (float2*)(ws + 20 * MiB);
        float*  hd   = (float*)(ws + 28 * MiB);
        int*    flag = (int*)(ws + 32 * MiB);

        hipMemsetAsync(ws, 0, 16 * MiB, stream);

        detect_kernel<<<1, 256, 0, stream>>>(ei, flag);
        deg_kernel<<<(nE + bs - 1) / bs, bs, 0, stream>>>(ei, deg, flag, nE);
        prep_kernel<<<(nN + bs - 1) / bs, bs, 0, stream>>>(deg, (const float2*)x, dinv, xd, nN);
        l1a_kernel<<<(nE + bs - 1) / bs, bs, 0, stream>>>(ei, xd, agg, flag, nE);
        h2f_kernel<<<(nN + bs - 1) / bs, bs, 0, stream>>>((const float2*)agg, xd, dinv,
                                                          W1, b1, W2, hd, nN);
        l2a_kernel<<<(nE + bs - 1) / bs, bs, 0, stream>>>(ei, hd, out2, flag, nE);
        finf_kernel<<<(nN + bs - 1) / bs, bs, 0, stream>>>(out2, hd, dinv, b2, out, nN);
    }
}

// Round 5
// 1025.907 us; speedup vs baseline: 1.1712x; 1.1694x over previous
//
#include <hip/hip_runtime.h>

#define NN 1000000
#define NE 32000000
#define SCAN_B 256

// bucket decomposition: bucket = d >> 11, 2048 nodes per bucket.
// Cost model (validated rounds 0-4): any pass making ~1 RANDOM 64B-line touch
// per edge costs ~350us (91G lines/s ~= 5.8 TB/s fabric, hit-level-invariant).
// L1/L2 gathers are structural (pull mode). passC's 4B random scatter is NOT:
// software write-combining via LDS tiling turns it into coalesced full-line
// writes (~0.1 line-touches/edge on the write side).
#define BK_SH 11
#define BK_SZ 2048
#define NB 489                       // ceil(NN / BK_SZ)
#define GAB 512                      // edge-chunk blocks for passes A and C
#define CHUNK 62500                  // 512 * 62500 = 32,000,000 exactly (div by 4)
#define NL (NB * GAB)                // hist length = 250368 (= 978 * 256)
#define NBS (NL / SCAN_B)            // 978 scan blocks (exact)
#define TILE 8192                    // passC write-combining tile (div by 4)
#define CB 512                       // passC threads

typedef int vi4 __attribute__((ext_vector_type(4)));

// ---- dtype detector: flag=1 if edge_index is int64, 0 if int32 ----
// int64 little-endian values < 2^31 have all-zero high (odd) words.
__global__ void detect_kernel(const int* __restrict__ ei, int* __restrict__ flag) {
    __shared__ int nz;
    if (threadIdx.x == 0) nz = 0;
    __syncthreads();
    int w = ei[2 * threadIdx.x + 1];
    if (w != 0) atomicAdd(&nz, 1);
    __syncthreads();
    if (threadIdx.x == 0) *flag = (nz == 0) ? 1 : 0;
}

// ---- pass A: per-block LDS histogram over buckets -> hist[b*GAB + g] ----
__global__ void passA_kernel(const int* __restrict__ ei, int* __restrict__ hist,
                             const int* __restrict__ flagp, int nE) {
    __shared__ int h[NB];
    int t = threadIdx.x;
    for (int b = t; b < NB; b += 512) h[b] = 0;
    __syncthreads();
    int shift = *flagp;
    int start = blockIdx.x * CHUNK;
    int end = min(start + CHUNK, nE);
    if (shift == 0) {
        const int* dstp = ei + nE;
        for (int i = start + (t << 2); i < end; i += 2048) {
            vi4 d = __builtin_nontemporal_load((const vi4*)(dstp + i));
            atomicAdd(&h[d.x >> BK_SH], 1);
            atomicAdd(&h[d.y >> BK_SH], 1);
            atomicAdd(&h[d.z >> BK_SH], 1);
            atomicAdd(&h[d.w >> BK_SH], 1);
        }
    } else {
        const int* dstp = ei + ((size_t)nE << 1);
        for (int i = start + t; i < end; i += 512) {
            int d = __builtin_nontemporal_load(dstp + ((size_t)i << 1));
            atomicAdd(&h[d >> BK_SH], 1);
        }
    }
    __syncthreads();
    for (int b = t; b < NB; b += 512)
        hist[(size_t)b * GAB + blockIdx.x] = h[b];
}

// ---- scan stage 1: per-block exclusive scan (in-place), block sums ----
__global__ void scan1_kernel(int* __restrict__ data, int* __restrict__ bsum, int n) {
    __shared__ int sm[SCAN_B];
    int t = threadIdx.x;
    int i = blockIdx.x * SCAN_B + t;
    int v = (i < n) ? data[i] : 0;
    sm[t] = v;
    __syncthreads();
    for (int o = 1; o < SCAN_B; o <<= 1) {
        int a = (t >= o) ? sm[t - o] : 0;
        __syncthreads();
        sm[t] += a;
        __syncthreads();
    }
    if (i < n) data[i] = sm[t] - v;
    if (t == SCAN_B - 1) bsum[blockIdx.x] = sm[t];
}

// ---- scan stage 2: exclusive scan of block sums (1 block, up to 4096) ----
__global__ void scan2_kernel(int* __restrict__ bsum, int nb) {
    __shared__ int sm[1024];
    int t = threadIdx.x;
    int base = t * 4;
    int v[4];
    int s = 0;
#pragma unroll
    for (int j = 0; j < 4; ++j) {
        v[j] = (base + j < nb) ? bsum[base + j] : 0;
        s += v[j];
    }
    sm[t] = s;
    __syncthreads();
    for (int o = 1; o < 1024; o <<= 1) {
        int a = (t >= o) ? sm[t - o] : 0;
        __syncthreads();
        sm[t] += a;
        __syncthreads();
    }
    int run = sm[t] - s;
#pragma unroll
    for (int j = 0; j < 4; ++j) {
        if (base + j < nb) bsum[base + j] = run;
        run += v[j];
    }
}

// ---- pass C: write-combining scatter of packed edges into bucket regions ----
// pairs[idx] = s | (d_local << 20)   (s < 2^20, d_local < 2^11)
// Per tile: LDS histogram -> scan -> bucket-major LDS staging -> coalesced
// flush into this block's PRIVATE per-bucket global sub-ranges (from hist).
__global__ void __launch_bounds__(CB, 2)
passC_kernel(const int* __restrict__ ei, const int* __restrict__ hist,
             const int* __restrict__ bsum, unsigned int* __restrict__ pairs,
             const int* __restrict__ flagp, int nE) {
    __shared__ int cnt[NB];
    __shared__ int scn[NB];
    __shared__ int off[NB];
    __shared__ int curb[NB];
    __shared__ int ssum[CB];
    __shared__ unsigned int stg[TILE];
    __shared__ unsigned short bkt[TILE];

    int t = threadIdx.x;
    for (int b = t; b < NB; b += CB) {
        int flat = b * GAB + blockIdx.x;
        curb[b] = hist[flat] + bsum[flat >> 8];
        cnt[b] = 0;
    }
    __syncthreads();
    int shift = *flagp;
    int start = blockIdx.x * CHUNK;
    int end = min(start + CHUNK, nE);
    const int* srcp = ei;
    const int* dstp = ei + nE;

    for (int ts = start; ts < end; ts += TILE) {
        int te = min(ts + TILE, end);
        int tn = te - ts;
        // phase 1: tile histogram of dst buckets (plain loads: keep in L2 for phase 3)
        if (shift == 0) {
            for (int i = ts + (t << 2); i + 4 <= te; i += (CB << 2)) {
                vi4 d = *(const vi4*)(dstp + i);
                atomicAdd(&cnt[d.x >> BK_SH], 1);
                atomicAdd(&cnt[d.y >> BK_SH], 1);
                atomicAdd(&cnt[d.z >> BK_SH], 1);
                atomicAdd(&cnt[d.w >> BK_SH], 1);
            }
            // tn is always divisible by 4 (CHUNK and TILE both are)
        } else {
            for (int i = ts + t; i < te; i += CB) {
                int d = ei[((size_t)(nE + i)) << 1];
                atomicAdd(&cnt[d >> BK_SH], 1);
            }
        }
        __syncthreads();
        // phase 2: 512-wide exclusive scan of cnt (NB=489 <= CB)
        {
            int v = (t < NB) ? cnt[t] : 0;
            ssum[t] = v;
            __syncthreads();
            for (int o = 1; o < CB; o <<= 1) {
                int a = (t >= o) ? ssum[t - o] : 0;
                __syncthreads();
                ssum[t] += a;
                __syncthreads();
            }
            if (t < NB) { scn[t] = ssum[t] - v; off[t] = 0; }
        }
        __syncthreads();
        // phase 3: scatter packed pairs into bucket-major LDS staging
        if (shift == 0) {
            for (int i = ts + (t << 2); i + 4 <= te; i += (CB << 2)) {
                vi4 s = *(const vi4*)(srcp + i);
                vi4 d = *(const vi4*)(dstp + i);
                int b, pos;
                b = d.x >> BK_SH; pos = scn[b] + atomicAdd(&off[b], 1);
                stg[pos] = (unsigned)s.x | ((unsigned)(d.x & (BK_SZ - 1)) << 20);
                bkt[pos] = (unsigned short)b;
                b = d.y >> BK_SH; pos = scn[b] + atomicAdd(&off[b], 1);
                stg[pos] = (unsigned)s.y | ((unsigned)(d.y & (BK_SZ - 1)) << 20);
                bkt[pos] = (unsigned short)b;
                b = d.z >> BK_SH; pos = scn[b] + atomicAdd(&off[b], 1);
                stg[pos] = (unsigned)s.z | ((unsigned)(d.z & (BK_SZ - 1)) << 20);
                bkt[pos] = (unsigned short)b;
                b = d.w >> BK_SH; pos = scn[b] + atomicAdd(&off[b], 1);
                stg[pos] = (unsigned)s.w | ((unsigned)(d.w & (BK_SZ - 1)) << 20);
                bkt[pos] = (unsigned short)b;
            }
        } else {
            for (int i = ts + t; i < te; i += CB) {
                int s = ei[(size_t)i << 1];
                int d = ei[((size_t)(nE + i)) << 1];
                int b = d >> BK_SH;
                int pos = scn[b] + atomicAdd(&off[b], 1);
                stg[pos] = (unsigned)s | ((unsigned)(d & (BK_SZ - 1)) << 20);
                bkt[pos] = (unsigned short)b;
            }
        }
        __syncthreads();
        // phase 4: coalesced flush (piecewise-contiguous runs per bucket)
        for (int j = t; j < tn; j += CB) {
            int b = bkt[j];
            pairs[curb[b] + (j - scn[b])] = stg[j];
        }
        __syncthreads();
        // advance cursors, reset counts for next tile
        for (int b = t; b < NB; b += CB) {
            curb[b] += cnt[b];
            cnt[b] = 0;
        }
        __syncthreads();
    }
}

__device__ __forceinline__ void bucket_range(const int* __restrict__ hist,
                                             const int* __restrict__ bsum,
                                             int b, int nE, int& base, int& endp) {
    int f0 = b * GAB;
    base = hist[f0] + bsum[f0 >> 8];
    if (b + 1 < NB) {
        int f1 = (b + 1) * GAB;
        endp = hist[f1] + bsum[f1 >> 8];
    } else {
        endp = nE;
    }
}

// aligned sweep bounds: [base, abase) scalar prologue (<=3), [abase, rend) in
// aligned vi4 quads, [rend, endp) scalar tail (<=3).
__device__ __forceinline__ void aligned_range(int base, int endp, int& abase, int& rend) {
    abase = (base + 3) & ~3;
    if (abase > endp) abase = endp;
    rend = abase + ((endp - abase) & ~3);
}

// ---- pass D0: per-bucket degree count -> dinv, xd = x * dinv ----
__global__ void passD0_kernel(const unsigned int* __restrict__ pairs,
                              const int* __restrict__ hist, const int* __restrict__ bsum,
                              const float2* __restrict__ x,
                              float* __restrict__ dinv, float2* __restrict__ xd,
                              int nE, int nN) {
    __shared__ int degl[BK_SZ];
    int t = threadIdx.x;
    int b = blockIdx.x;
    for (int j = t; j < BK_SZ; j += 1024) degl[j] = 0;
    __syncthreads();
    int base, endp, abase, rend;
    bucket_range(hist, bsum, b, nE, base, endp);
    aligned_range(base, endp, abase, rend);
    // prologue + tail (scalar, <=3 each)
    {
        int k = base + t;
        if (k < abase) atomicAdd(&degl[pairs[k] >> 20], 1);
        int k2 = rend + t;
        if (k2 < endp) atomicAdd(&degl[pairs[k2] >> 20], 1);
    }
    for (int k = abase + (t << 2); k + 4 <= rend; k += 4096) {
        vi4 q = *(const vi4*)(pairs + k);
        atomicAdd(&degl[(unsigned)q.x >> 20], 1);
        atomicAdd(&degl[(unsigned)q.y >> 20], 1);
        atomicAdd(&degl[(unsigned)q.z >> 20], 1);
        atomicAdd(&degl[(unsigned)q.w >> 20], 1);
    }
    __syncthreads();
    for (int j = t; j < BK_SZ; j += 1024) {
        int nid = (b << BK_SH) + j;
        if (nid < nN) {
            float di = rsqrtf((float)(degl[j] + 1));   // +1 self-loop
            dinv[nid] = di;
            float2 v = x[nid];
            xd[nid] = make_float2(v.x * di, v.y * di);
        }
    }
}

// ---- pass L1: per-bucket aggregate xd, fuse W1/b1/relu/W2 -> hd = h2*dinv ----
__global__ void passL1_kernel(const unsigned int* __restrict__ pairs,
                              const int* __restrict__ hist, const int* __restrict__ bsum,
                              const float* __restrict__ dinv, const float2* __restrict__ xd,
                              const float* __restrict__ W1, const float* __restrict__ b1,
                              const float* __restrict__ W2,
                              float* __restrict__ hd, int nE, int nN) {
    __shared__ float ax[BK_SZ];
    __shared__ float ay[BK_SZ];
    int t = threadIdx.x;
    int b = blockIdx.x;
    for (int j = t; j < BK_SZ; j += 1024) { ax[j] = 0.f; ay[j] = 0.f; }
    __syncthreads();
    int base, endp, abase, rend;
    bucket_range(hist, bsum, b, nE, base, endp);
    aligned_range(base, endp, abase, rend);
    {
        int k = base + t;
        if (k < abase) {
            unsigned int p = pairs[k];
            float2 v = xd[p & 0xFFFFF];
            atomicAdd(&ax[p >> 20], v.x);
            atomicAdd(&ay[p >> 20], v.y);
        }
        int k2 = rend + t;
        if (k2 < endp) {
            unsigned int p = pairs[k2];
            float2 v = xd[p & 0xFFFFF];
            atomicAdd(&ax[p >> 20], v.x);
            atomicAdd(&ay[p >> 20], v.y);
        }
    }
    for (int k = abase + (t << 2); k + 4 <= rend; k += 4096) {
        vi4 q = *(const vi4*)(pairs + k);
        unsigned int p[4] = {(unsigned)q.x, (unsigned)q.y, (unsigned)q.z, (unsigned)q.w};
        float2 v[4];
#pragma unroll
        for (int j = 0; j < 4; ++j) v[j] = xd[p[j] & 0xFFFFF];
#pragma unroll
        for (int j = 0; j < 4; ++j) {
            int dl = p[j] >> 20;
            atomicAdd(&ax[dl], v[j].x);
            atomicAdd(&ay[dl], v[j].y);
        }
    }
    __syncthreads();
    for (int j = t; j < BK_SZ; j += 1024) {
        int nid = (b << BK_SH) + j;
        if (nid < nN) {
            float dd = dinv[nid];
            float2 xs = xd[nid];
            float AX = (ax[j] + xs.x * dd) * dd;       // self-loop: xd*dd
            float AY = (ay[j] + xs.y * dd) * dd;
            float acc = 0.f;
#pragma unroll
            for (int c = 0; c < 8; ++c) {
                float h = fmaf(AX, W1[c], fmaf(AY, W1[8 + c], b1[c]));
                acc = fmaf(fmaxf(h, 0.f), W2[c], acc);
            }
            hd[nid] = acc * dd;                        // hd = h2 * dinv
        }
    }
}

// ---- pass L2: per-bucket aggregate hd, fuse sigmoid -> out ----
__global__ void passL2_kernel(const unsigned int* __restrict__ pairs,
                              const int* __restrict__ hist, const int* __restrict__ bsum,
                              const float* __restrict__ dinv, const float* __restrict__ hd,
                              const float* __restrict__ b2,
                              float* __restrict__ out, int nE, int nN) {
    __shared__ float ag[BK_SZ];
    int t = threadIdx.x;
    int b = blockIdx.x;
    for (int j = t; j < BK_SZ; j += 1024) ag[j] = 0.f;
    __syncthreads();
    int base, endp, abase, rend;
    bucket_range(hist, bsum, b, nE, base, endp);
    aligned_range(base, endp, abase, rend);
    {
        int k = base + t;
        if (k < abase) {
            unsigned int p = pairs[k];
            atomicAdd(&ag[p >> 20], hd[p & 0xFFFFF]);
        }
        int k2 = rend + t;
        if (k2 < endp) {
            unsigned int p = pairs[k2];
            atomicAdd(&ag[p >> 20], hd[p & 0xFFFFF]);
        }
    }
    for (int k = abase + (t << 2); k + 4 <= rend; k += 4096) {
        vi4 q = *(const vi4*)(pairs + k);
        unsigned int p[4] = {(unsigned)q.x, (unsigned)q.y, (unsigned)q.z, (unsigned)q.w};
        float v[4];
#pragma unroll
        for (int j = 0; j < 4; ++j) v[j] = hd[p[j] & 0xFFFFF];
#pragma unroll
        for (int j = 0; j < 4; ++j) atomicAdd(&ag[p[j] >> 20], v[j]);
    }
    __syncthreads();
    for (int j = t; j < BK_SZ; j += 1024) {
        int nid = (b << BK_SH) + j;
        if (nid < nN) {
            float z = fmaf(dinv[nid], ag[j] + hd[nid], b2[0]);
            out[nid] = 1.f / (1.f + expf(-z));
        }
    }
}

// ================= fallback (small-workspace) atomic path =================

__global__ void deg_kernel(const int* __restrict__ ei, int* __restrict__ deg,
                           const int* __restrict__ flagp, int nE) {
    int i = blockIdx.x * blockDim.x + threadIdx.x;
    if (i >= nE) return;
    int shift = *flagp;
    int d = ei[((size_t)nE << shift) + ((size_t)i << shift)];
    atomicAdd(&deg[d], 1);
}

__global__ void prep_kernel(const int* __restrict__ deg, const float2* __restrict__ x,
                            float* __restrict__ dinv, float2* __restrict__ xd, int nN) {
    int i = blockIdx.x * blockDim.x + threadIdx.x;
    if (i >= nN) return;
    float di = rsqrtf((float)(deg[i] + 1));
    dinv[i] = di;
    float2 v = x[i];
    xd[i] = make_float2(v.x * di, v.y * di);
}

__device__ __forceinline__ void load_edge(const int* __restrict__ ei, int shift,
                                          int nE, int i, int& s, int& d) {
    s = ei[(size_t)i << shift];
    d = ei[((size_t)nE << shift) + ((size_t)i << shift)];
}

__global__ void l1a_kernel(const int* __restrict__ ei, const float2* __restrict__ xd,
                           float* __restrict__ agg, const int* __restrict__ flagp, int nE) {
    int i = blockIdx.x * blockDim.x + threadIdx.x;
    if (i >= nE) return;
    int shift = *flagp;
    int s, d;
    load_edge(ei, shift, nE, i, s, d);
    float2 v = xd[s];
    unsafeAtomicAdd(&agg[(size_t)d * 2], v.x);
    unsafeAtomicAdd(&agg[(size_t)d * 2 + 1], v.y);
}

__global__ void h2f_kernel(const float2* __restrict__ agg, const float2* __restrict__ xd,
                           const float* __restrict__ dinv, const float* __restrict__ W1,
                           const float* __restrict__ b1, const float* __restrict__ W2,
                           float* __restrict__ hd, int nN) {
    int d = blockIdx.x * blockDim.x + threadIdx.x;
    if (d >= nN) return;
    float dd = dinv[d];
    float2 a = agg[d];
    float2 xs = xd[d];
    float ax = (a.x + xs.x * dd) * dd;
    float ay = (a.y + xs.y * dd) * dd;
    float acc = 0.f;
#pragma unroll
    for (int j = 0; j < 8; ++j) {
        float h = fmaf(ax, W1[j], fmaf(ay, W1[8 + j], b1[j]));
        acc = fmaf(fmaxf(h, 0.f), W2[j], acc);
    }
    hd[d] = acc * dd;
}

__global__ void l2a_kernel(const int* __restrict__ ei, const float* __restrict__ hd,
                           float* __restrict__ out2, const int* __restrict__ flagp, int nE) {
    int i = blockIdx.x * blockDim.x + threadIdx.x;
    if (i >= nE) return;
    int shift = *flagp;
    int s, d;
    load_edge(ei, shift, nE, i, s, d);
    unsafeAtomicAdd(&out2[d], hd[s]);
}

__global__ void finf_kernel(const float* __restrict__ out2, const float* __restrict__ hd,
                            const float* __restrict__ dinv, const float* __restrict__ b2,
                            float* __restrict__ out, int nN) {
    int d = blockIdx.x * blockDim.x + threadIdx.x;
    if (d >= nN) return;
    float z = fmaf(dinv[d], out2[d] + hd[d], b2[0]);
    out[d] = 1.f / (1.f + expf(-z));
}

extern "C" void kernel_launch(void* const* d_in, const int* in_sizes, int n_in,
                              void* d_out, int out_size, void* d_ws, size_t ws_size,
                              hipStream_t stream) {
    const float* x  = (const float*)d_in[0];
    const int*   ei = (const int*)d_in[1];
    const float* W1 = (const float*)d_in[2];
    const float* b1 = (const float*)d_in[3];
    const float* W2 = (const float*)d_in[4];
    const float* b2 = (const float*)d_in[5];
    float* out = (float*)d_out;

    const int nE = NE, nN = NN;
    const int bs = 256;
    char* ws = (char*)d_ws;
    const size_t MiB = 1 << 20;

    // bucket-path layout: hist@0 (0.96MiB)  bsum@1MiB  flag@1MiB+64K
    //                     dinv@2MiB  xd@6MiB  hd@14MiB  pairs@18MiB (128MB)
    const size_t csr_need = 18 * MiB + (size_t)nE * 4;

    if (ws_size >= csr_need) {
        int*          hist  = (int*)ws;
        int*          bsum  = (int*)(ws + 1 * MiB);
        int*          flag  = (int*)(ws + 1 * MiB + 65536);
        float*        dinv  = (float*)(ws + 2 * MiB);
        float2*       xd    = (float2*)(ws + 6 * MiB);
        float*        hd    = (float*)(ws + 14 * MiB);
        unsigned int* pairs = (unsigned int*)(ws + 18 * MiB);

        detect_kernel<<<1, 256, 0, stream>>>(ei, flag);
        passA_kernel<<<GAB, 512, 0, stream>>>(ei, hist, flag, nE);
        scan1_kernel<<<NBS, SCAN_B, 0, stream>>>(hist, bsum, NL);
        scan2_kernel<<<1, 1024, 0, stream>>>(bsum, NBS);
        passC_kernel<<<GAB, CB, 0, stream>>>(ei, hist, bsum, pairs, flag, nE);
        passD0_kernel<<<NB, 1024, 0, stream>>>(pairs, hist, bsum, (const float2*)x,
                                               dinv, xd, nE, nN);
        passL1_kernel<<<NB, 1024, 0, stream>>>(pairs, hist, bsum, dinv, xd,
                                               W1, b1, W2, hd, nE, nN);
        passL2_kernel<<<NB, 1024, 0, stream>>>(pairs, hist, bsum, dinv, hd,
                                               b2, out, nE, nN);
    } else {
        // fallback layout: deg@0  agg@4..12  out2@12  dinv@16  xd@20..28  hd@28  flag@32MiB
        int*    deg  = (int*)ws;
        float*  agg  = (float*)(ws + 4 * MiB);
        float*  out2 = (float*)(ws + 12 * MiB);
        float*  dinv = (float*)(ws + 16 * MiB);
        float2* xd   = (float2*)(ws + 20 * MiB);
        float*  hd   = (float*)(ws + 28 * MiB);
        int*    flag = (int*)(ws + 32 * MiB);

        hipMemsetAsync(ws, 0, 16 * MiB, stream);

        detect_kernel<<<1, 256, 0, stream>>>(ei, flag);
        deg_kernel<<<(nE + bs - 1) / bs, bs, 0, stream>>>(ei, deg, flag, nE);
        prep_kernel<<<(nN + bs - 1) / bs, bs, 0, stream>>>(deg, (const float2*)x, dinv, xd, nN);
        l1a_kernel<<<(nE + bs - 1) / bs, bs, 0, stream>>>(ei, xd, agg, flag, nE);
        h2f_kernel<<<(nN + bs - 1) / bs, bs, 0, stream>>>((const float2*)agg, xd, dinv,
                                                          W1, b1, W2, hd, nN);
        l2a_kernel<<<(nE + bs - 1) / bs, bs, 0, stream>>>(ei, hd, out2, flag, nE);
        finf_kernel<<<(nN + bs - 1) / bs, bs, 0, stream>>>(out2, hd, dinv, b2, out, nN);
    }
}

// Round 6
// 996.391 us; speedup vs baseline: 1.2059x; 1.0296x over previous
//
#include <hip/hip_runtime.h>

#define NN 1000000
#define NE 32000000
#define SCAN_B 256

// bucket decomposition: bucket = d >> 11, 2048 nodes per bucket.
// Cost model (validated rounds 0-5): any pass making ~1 RANDOM 64B-line touch
// per edge costs ~350us (91G lines/s, hit-level/occupancy/MLP-invariant).
// L1/L2 gathers are structural (pull mode). passC is write-combined via LDS
// tiling. NOTE: edge_index is int64 in practice -> the shift==1 branches are
// the LIVE path; they use vi4 loads (2 edges per 16B load).
#define BK_SH 11
#define BK_SZ 2048
#define NB 489                       // ceil(NN / BK_SZ)
#define GAB 512                      // edge-chunk blocks for passes A and C
#define CHUNK 62500                  // 512 * 62500 = 32,000,000 exactly (div by 4)
#define NL (NB * GAB)                // hist length = 250368 (= 978 * 256)
#define NBS (NL / SCAN_B)            // 978 scan blocks (exact)
#define TILE 8192                    // passC write-combining tile (div by 4)
#define CB 512                       // passC threads

typedef int vi4 __attribute__((ext_vector_type(4)));

// ---- dtype detector: flag=1 if edge_index is int64, 0 if int32 ----
// int64 little-endian values < 2^31 have all-zero high (odd) words.
__global__ void detect_kernel(const int* __restrict__ ei, int* __restrict__ flag) {
    __shared__ int nz;
    if (threadIdx.x == 0) nz = 0;
    __syncthreads();
    int w = ei[2 * threadIdx.x + 1];
    if (w != 0) atomicAdd(&nz, 1);
    __syncthreads();
    if (threadIdx.x == 0) *flag = (nz == 0) ? 1 : 0;
}

// ---- pass A: per-block LDS histogram over buckets -> hist[b*GAB + g] ----
__global__ void passA_kernel(const int* __restrict__ ei, int* __restrict__ hist,
                             const int* __restrict__ flagp, int nE) {
    __shared__ int h[NB];
    int t = threadIdx.x;
    for (int b = t; b < NB; b += 512) h[b] = 0;
    __syncthreads();
    int shift = *flagp;
    int start = blockIdx.x * CHUNK;
    int end = min(start + CHUNK, nE);
    if (shift == 0) {
        const int* dstp = ei + nE;
        for (int i = start + (t << 2); i < end; i += 2048) {
            vi4 d = __builtin_nontemporal_load((const vi4*)(dstp + i));
            atomicAdd(&h[d.x >> BK_SH], 1);
            atomicAdd(&h[d.y >> BK_SH], 1);
            atomicAdd(&h[d.z >> BK_SH], 1);
            atomicAdd(&h[d.w >> BK_SH], 1);
        }
    } else {
        // int64: one vi4 = 2 edges ({lo,hi} pairs); extract .x and .z
        const int* dstp = ei + ((size_t)nE << 1);
        for (int i = start + (t << 1); i < end; i += 1024) {
            vi4 d2 = __builtin_nontemporal_load((const vi4*)(dstp + ((size_t)i << 1)));
            atomicAdd(&h[d2.x >> BK_SH], 1);
            atomicAdd(&h[d2.z >> BK_SH], 1);
        }
    }
    __syncthreads();
    for (int b = t; b < NB; b += 512)
        hist[(size_t)b * GAB + blockIdx.x] = h[b];
}

// ---- scan stage 1: per-block exclusive scan (in-place), block sums ----
__global__ void scan1_kernel(int* __restrict__ data, int* __restrict__ bsum, int n) {
    __shared__ int sm[SCAN_B];
    int t = threadIdx.x;
    int i = blockIdx.x * SCAN_B + t;
    int v = (i < n) ? data[i] : 0;
    sm[t] = v;
    __syncthreads();
    for (int o = 1; o < SCAN_B; o <<= 1) {
        int a = (t >= o) ? sm[t - o] : 0;
        __syncthreads();
        sm[t] += a;
        __syncthreads();
    }
    if (i < n) data[i] = sm[t] - v;
    if (t == SCAN_B - 1) bsum[blockIdx.x] = sm[t];
}

// ---- scan stage 2: exclusive scan of block sums (1 block, up to 4096) ----
__global__ void scan2_kernel(int* __restrict__ bsum, int nb) {
    __shared__ int sm[1024];
    int t = threadIdx.x;
    int base = t * 4;
    int v[4];
    int s = 0;
#pragma unroll
    for (int j = 0; j < 4; ++j) {
        v[j] = (base + j < nb) ? bsum[base + j] : 0;
        s += v[j];
    }
    sm[t] = s;
    __syncthreads();
    for (int o = 1; o < 1024; o <<= 1) {
        int a = (t >= o) ? sm[t - o] : 0;
        __syncthreads();
        sm[t] += a;
        __syncthreads();
    }
    int run = sm[t] - s;
#pragma unroll
    for (int j = 0; j < 4; ++j) {
        if (base + j < nb) bsum[base + j] = run;
        run += v[j];
    }
}

// ---- passC tile scan: wave-level shfl scan of cnt[] -> scn[], off[]=0 ----
__device__ __forceinline__ void tile_scan(int t, int lane, int wid,
                                          int* __restrict__ cnt, int* __restrict__ scn,
                                          int* __restrict__ off, int* __restrict__ wsum) {
    int v = (t < NB) ? cnt[t] : 0;
    int sw = v;
#pragma unroll
    for (int o = 1; o < 64; o <<= 1) {
        int n = __shfl_up(sw, o, 64);
        if (lane >= o) sw += n;
    }
    if (lane == 63) wsum[wid] = sw;
    __syncthreads();
    if (t < 8) {
        int w = wsum[t];
        int iw = w;
#pragma unroll
        for (int o = 1; o < 8; o <<= 1) {
            int n = __shfl_up(iw, o, 8);
            if (t >= o) iw += n;
        }
        wsum[t] = iw - w;   // exclusive wave offset
    }
    __syncthreads();
    if (t < NB) { scn[t] = wsum[wid] + sw - v; off[t] = 0; }
    __syncthreads();
}

// ---- pass C: write-combining scatter of packed edges into bucket regions ----
// pairs[idx] = s | (d_local << 20)   (s < 2^20, d_local < 2^11)
// Per tile: reg-stash dst + LDS histogram -> shfl scan -> bucket-major LDS
// staging -> coalesced flush into this block's PRIVATE per-bucket sub-ranges.
__global__ void __launch_bounds__(CB, 2)
passC_kernel(const int* __restrict__ ei, const int* __restrict__ hist,
             const int* __restrict__ bsum, unsigned int* __restrict__ pairs,
             const int* __restrict__ flagp, int nE) {
    __shared__ int cnt[NB];
    __shared__ int scn[NB];
    __shared__ int off[NB];
    __shared__ int curb[NB];
    __shared__ int wsum[8];
    __shared__ unsigned int stg[TILE];
    __shared__ unsigned short bkt[TILE];

    int t = threadIdx.x;
    int lane = t & 63, wid = t >> 6;
    for (int b = t; b < NB; b += CB) {
        int flat = b * GAB + blockIdx.x;
        curb[b] = hist[flat] + bsum[flat >> 8];
        cnt[b] = 0;
    }
    __syncthreads();
    int shift = *flagp;
    int start = blockIdx.x * CHUNK;
    int end = min(start + CHUNK, nE);

    if (shift == 1) {
        // ---- int64 path (LIVE): 2 edges per vi4, dst stashed in registers ----
        const size_t dbase = (size_t)nE << 1;
        for (int ts = start; ts < end; ts += TILE) {
            int te = min(ts + TILE, end);
            int tn = te - ts;
            vi4 dd[8];
            // phase 1: histogram (stash dst words)
#pragma unroll
            for (int q = 0; q < 8; ++q) {
                int i = ts + (t << 1) + (q << 10);
                if (i + 2 <= te) {
                    dd[q] = __builtin_nontemporal_load(
                        (const vi4*)(ei + dbase + ((size_t)i << 1)));
                    atomicAdd(&cnt[dd[q].x >> BK_SH], 1);
                    atomicAdd(&cnt[dd[q].z >> BK_SH], 1);
                }
            }
            __syncthreads();
            tile_scan(t, lane, wid, cnt, scn, off, wsum);
            // phase 3: load src once, scatter into bucket-major staging
#pragma unroll
            for (int q = 0; q < 8; ++q) {
                int i = ts + (t << 1) + (q << 10);
                if (i + 2 <= te) {
                    vi4 ss = __builtin_nontemporal_load(
                        (const vi4*)(ei + ((size_t)i << 1)));
                    int b0 = dd[q].x >> BK_SH;
                    int pos = scn[b0] + atomicAdd(&off[b0], 1);
                    stg[pos] = (unsigned)ss.x | ((unsigned)(dd[q].x & (BK_SZ - 1)) << 20);
                    bkt[pos] = (unsigned short)b0;
                    int b1 = dd[q].z >> BK_SH;
                    pos = scn[b1] + atomicAdd(&off[b1], 1);
                    stg[pos] = (unsigned)ss.z | ((unsigned)(dd[q].z & (BK_SZ - 1)) << 20);
                    bkt[pos] = (unsigned short)b1;
                }
            }
            __syncthreads();
            // phase 4: coalesced flush
            for (int j = t; j < tn; j += CB) {
                int b = bkt[j];
                pairs[curb[b] + (j - scn[b])] = stg[j];
            }
            __syncthreads();
            for (int b = t; b < NB; b += CB) { curb[b] += cnt[b]; cnt[b] = 0; }
            __syncthreads();
        }
    } else {
        // ---- int32 path: 4 edges per vi4, dst stashed ----
        const int* srcp = ei;
        const int* dstp = ei + nE;
        for (int ts = start; ts < end; ts += TILE) {
            int te = min(ts + TILE, end);
            int tn = te - ts;
            vi4 dd[4];
#pragma unroll
            for (int q = 0; q < 4; ++q) {
                int i = ts + (t << 2) + (q << 11);
                if (i + 4 <= te) {
                    dd[q] = __builtin_nontemporal_load((const vi4*)(dstp + i));
                    atomicAdd(&cnt[dd[q].x >> BK_SH], 1);
                    atomicAdd(&cnt[dd[q].y >> BK_SH], 1);
                    atomicAdd(&cnt[dd[q].z >> BK_SH], 1);
                    atomicAdd(&cnt[dd[q].w >> BK_SH], 1);
                }
            }
            __syncthreads();
            tile_scan(t, lane, wid, cnt, scn, off, wsum);
#pragma unroll
            for (int q = 0; q < 4; ++q) {
                int i = ts + (t << 2) + (q << 11);
                if (i + 4 <= te) {
                    vi4 ss = __builtin_nontemporal_load((const vi4*)(srcp + i));
                    int dv[4] = {dd[q].x, dd[q].y, dd[q].z, dd[q].w};
                    int sv[4] = {ss.x, ss.y, ss.z, ss.w};
#pragma unroll
                    for (int e = 0; e < 4; ++e) {
                        int b = dv[e] >> BK_SH;
                        int pos = scn[b] + atomicAdd(&off[b], 1);
                        stg[pos] = (unsigned)sv[e] | ((unsigned)(dv[e] & (BK_SZ - 1)) << 20);
                        bkt[pos] = (unsigned short)b;
                    }
                }
            }
            __syncthreads();
            for (int j = t; j < tn; j += CB) {
                int b = bkt[j];
                pairs[curb[b] + (j - scn[b])] = stg[j];
            }
            __syncthreads();
            for (int b = t; b < NB; b += CB) { curb[b] += cnt[b]; cnt[b] = 0; }
            __syncthreads();
        }
    }
}

__device__ __forceinline__ void bucket_range(const int* __restrict__ hist,
                                             const int* __restrict__ bsum,
                                             int b, int nE, int& base, int& endp) {
    int f0 = b * GAB;
    base = hist[f0] + bsum[f0 >> 8];
    if (b + 1 < NB) {
        int f1 = (b + 1) * GAB;
        endp = hist[f1] + bsum[f1 >> 8];
    } else {
        endp = nE;
    }
}

// aligned sweep bounds: [base, abase) scalar prologue (<=3), [abase, rend) in
// aligned vi4 quads, [rend, endp) scalar tail (<=3).
__device__ __forceinline__ void aligned_range(int base, int endp, int& abase, int& rend) {
    abase = (base + 3) & ~3;
    if (abase > endp) abase = endp;
    rend = abase + ((endp - abase) & ~3);
}

// ---- pass D0: per-bucket degree count -> dinv, xd = x * dinv ----
__global__ void passD0_kernel(const unsigned int* __restrict__ pairs,
                              const int* __restrict__ hist, const int* __restrict__ bsum,
                              const float2* __restrict__ x,
                              float* __restrict__ dinv, float2* __restrict__ xd,
                              int nE, int nN) {
    __shared__ int degl[BK_SZ];
    int t = threadIdx.x;
    int b = blockIdx.x;
    for (int j = t; j < BK_SZ; j += 1024) degl[j] = 0;
    __syncthreads();
    int base, endp, abase, rend;
    bucket_range(hist, bsum, b, nE, base, endp);
    aligned_range(base, endp, abase, rend);
    // prologue + tail (scalar, <=3 each)
    {
        int k = base + t;
        if (k < abase) atomicAdd(&degl[pairs[k] >> 20], 1);
        int k2 = rend + t;
        if (k2 < endp) atomicAdd(&degl[pairs[k2] >> 20], 1);
    }
    for (int k = abase + (t << 2); k + 4 <= rend; k += 4096) {
        vi4 q = *(const vi4*)(pairs + k);
        atomicAdd(&degl[(unsigned)q.x >> 20], 1);
        atomicAdd(&degl[(unsigned)q.y >> 20], 1);
        atomicAdd(&degl[(unsigned)q.z >> 20], 1);
        atomicAdd(&degl[(unsigned)q.w >> 20], 1);
    }
    __syncthreads();
    for (int j = t; j < BK_SZ; j += 1024) {
        int nid = (b << BK_SH) + j;
        if (nid < nN) {
            float di = rsqrtf((float)(degl[j] + 1));   // +1 self-loop
            dinv[nid] = di;
            float2 v = x[nid];
            xd[nid] = make_float2(v.x * di, v.y * di);
        }
    }
}

// ---- pass L1: per-bucket aggregate xd, fuse W1/b1/relu/W2 -> hd = h2*dinv ----
__global__ void passL1_kernel(const unsigned int* __restrict__ pairs,
                              const int* __restrict__ hist, const int* __restrict__ bsum,
                              const float* __restrict__ dinv, const float2* __restrict__ xd,
                              const float* __restrict__ W1, const float* __restrict__ b1,
                              const float* __restrict__ W2,
                              float* __restrict__ hd, int nE, int nN) {
    __shared__ float ax[BK_SZ];
    __shared__ float ay[BK_SZ];
    int t = threadIdx.x;
    int b = blockIdx.x;
    for (int j = t; j < BK_SZ; j += 1024) { ax[j] = 0.f; ay[j] = 0.f; }
    __syncthreads();
    int base, endp, abase, rend;
    bucket_range(hist, bsum, b, nE, base, endp);
    aligned_range(base, endp, abase, rend);
    {
        int k = base + t;
        if (k < abase) {
            unsigned int p = pairs[k];
            float2 v = xd[p & 0xFFFFF];
            atomicAdd(&ax[p >> 20], v.x);
            atomicAdd(&ay[p >> 20], v.y);
        }
        int k2 = rend + t;
        if (k2 < endp) {
            unsigned int p = pairs[k2];
            float2 v = xd[p & 0xFFFFF];
            atomicAdd(&ax[p >> 20], v.x);
            atomicAdd(&ay[p >> 20], v.y);
        }
    }
    for (int k = abase + (t << 2); k + 4 <= rend; k += 4096) {
        vi4 q = *(const vi4*)(pairs + k);
        unsigned int p[4] = {(unsigned)q.x, (unsigned)q.y, (unsigned)q.z, (unsigned)q.w};
        float2 v[4];
#pragma unroll
        for (int j = 0; j < 4; ++j) v[j] = xd[p[j] & 0xFFFFF];
#pragma unroll
        for (int j = 0; j < 4; ++j) {
            int dl = p[j] >> 20;
            atomicAdd(&ax[dl], v[j].x);
            atomicAdd(&ay[dl], v[j].y);
        }
    }
    __syncthreads();
    for (int j = t; j < BK_SZ; j += 1024) {
        int nid = (b << BK_SH) + j;
        if (nid < nN) {
            float dd = dinv[nid];
            float2 xs = xd[nid];
            float AX = (ax[j] + xs.x * dd) * dd;       // self-loop: xd*dd
            float AY = (ay[j] + xs.y * dd) * dd;
            float acc = 0.f;
#pragma unroll
            for (int c = 0; c < 8; ++c) {
                float h = fmaf(AX, W1[c], fmaf(AY, W1[8 + c], b1[c]));
                acc = fmaf(fmaxf(h, 0.f), W2[c], acc);
            }
            hd[nid] = acc * dd;                        // hd = h2 * dinv
        }
    }
}

// ---- pass L2: per-bucket aggregate hd, fuse sigmoid -> out ----
__global__ void passL2_kernel(const unsigned int* __restrict__ pairs,
                              const int* __restrict__ hist, const int* __restrict__ bsum,
                              const float* __restrict__ dinv, const float* __restrict__ hd,
                              const float* __restrict__ b2,
                              float* __restrict__ out, int nE, int nN) {
    __shared__ float ag[BK_SZ];
    int t = threadIdx.x;
    int b = blockIdx.x;
    for (int j = t; j < BK_SZ; j += 1024) ag[j] = 0.f;
    __syncthreads();
    int base, endp, abase, rend;
    bucket_range(hist, bsum, b, nE, base, endp);
    aligned_range(base, endp, abase, rend);
    {
        int k = base + t;
        if (k < abase) {
            unsigned int p = pairs[k];
            atomicAdd(&ag[p >> 20], hd[p & 0xFFFFF]);
        }
        int k2 = rend + t;
        if (k2 < endp) {
            unsigned int p = pairs[k2];
            atomicAdd(&ag[p >> 20], hd[p & 0xFFFFF]);
        }
    }
    for (int k = abase + (t << 2); k + 4 <= rend; k += 4096) {
        vi4 q = *(const vi4*)(pairs + k);
        unsigned int p[4] = {(unsigned)q.x, (unsigned)q.y, (unsigned)q.z, (unsigned)q.w};
        float v[4];
#pragma unroll
        for (int j = 0; j < 4; ++j) v[j] = hd[p[j] & 0xFFFFF];
#pragma unroll
        for (int j = 0; j < 4; ++j) atomicAdd(&ag[p[j] >> 20], v[j]);
    }
    __syncthreads();
    for (int j = t; j < BK_SZ; j += 1024) {
        int nid = (b << BK_SH) + j;
        if (nid < nN) {
            float z = fmaf(dinv[nid], ag[j] + hd[nid], b2[0]);
            out[nid] = 1.f / (1.f + expf(-z));
        }
    }
}

// ================= fallback (small-workspace) atomic path =================

__global__ void deg_kernel(const int* __restrict__ ei, int* __restrict__ deg,
                           const int* __restrict__ flagp, int nE) {
    int i = blockIdx.x * blockDim.x + threadIdx.x;
    if (i >= nE) return;
    int shift = *flagp;
    int d = ei[((size_t)nE << shift) + ((size_t)i << shift)];
    atomicAdd(&deg[d], 1);
}

__global__ void prep_kernel(const int* __restrict__ deg, const float2* __restrict__ x,
                            float* __restrict__ dinv, float2* __restrict__ xd, int nN) {
    int i = blockIdx.x * blockDim.x + threadIdx.x;
    if (i >= nN) return;
    float di = rsqrtf((float)(deg[i] + 1));
    dinv[i] = di;
    float2 v = x[i];
    xd[i] = make_float2(v.x * di, v.y * di);
}

__device__ __forceinline__ void load_edge(const int* __restrict__ ei, int shift,
                                          int nE, int i, int& s, int& d) {
    s = ei[(size_t)i << shift];
    d = ei[((size_t)nE << shift) + ((size_t)i << shift)];
}

__global__ void l1a_kernel(const int* __restrict__ ei, const float2* __restrict__ xd,
                           float* __restrict__ agg, const int* __restrict__ flagp, int nE) {
    int i = blockIdx.x * blockDim.x + threadIdx.x;
    if (i >= nE) return;
    int shift = *flagp;
    int s, d;
    load_edge(ei, shift, nE, i, s, d);
    float2 v = xd[s];
    unsafeAtomicAdd(&agg[(size_t)d * 2], v.x);
    unsafeAtomicAdd(&agg[(size_t)d * 2 + 1], v.y);
}

__global__ void h2f_kernel(const float2* __restrict__ agg, const float2* __restrict__ xd,
                           const float* __restrict__ dinv, const float* __restrict__ W1,
                           const float* __restrict__ b1, const float* __restrict__ W2,
                           float* __restrict__ hd, int nN) {
    int d = blockIdx.x * blockDim.x + threadIdx.x;
    if (d >= nN) return;
    float dd = dinv[d];
    float2 a = agg[d];
    float2 xs = xd[d];
    float ax = (a.x + xs.x * dd) * dd;
    float ay = (a.y + xs.y * dd) * dd;
    float acc = 0.f;
#pragma unroll
    for (int j = 0; j < 8; ++j) {
        float h = fmaf(ax, W1[j], fmaf(ay, W1[8 + j], b1[j]));
        acc = fmaf(fmaxf(h, 0.f), W2[j], acc);
    }
    hd[d] = acc * dd;
}

__global__ void l2a_kernel(const int* __restrict__ ei, const float* __restrict__ hd,
                           float* __restrict__ out2, const int* __restrict__ flagp, int nE) {
    int i = blockIdx.x * blockDim.x + threadIdx.x;
    if (i >= nE) return;
    int shift = *flagp;
    int s, d;
    load_edge(ei, shift, nE, i, s, d);
    unsafeAtomicAdd(&out2[d], hd[s]);
}

__global__ void finf_kernel(const float* __restrict__ out2, const float* __restrict__ hd,
                            const float* __restrict__ dinv, const float* __restrict__ b2,
                            float* __restrict__ out, int nN) {
    int d = blockIdx.x * blockDim.x + threadIdx.x;
    if (d >= nN) return;
    float z = fmaf(dinv[d], out2[d] + hd[d], b2[0]);
    out[d] = 1.f / (1.f + expf(-z));
}

extern "C" void kernel_launch(void* const* d_in, const int* in_sizes, int n_in,
                              void* d_out, int out_size, void* d_ws, size_t ws_size,
                              hipStream_t stream) {
    const float* x  = (const float*)d_in[0];
    const int*   ei = (const int*)d_in[1];
    const float* W1 = (const float*)d_in[2];
    const float* b1 = (const float*)d_in[3];
    const float* W2 = (const float*)d_in[4];
    const float* b2 = (const float*)d_in[5];
    float* out = (float*)d_out;

    const int nE = NE, nN = NN;
    const int bs = 256;
    char* ws = (char*)d_ws;
    const size_t MiB = 1 << 20;

    // bucket-path layout: hist@0 (0.96MiB)  bsum@1MiB  flag@1MiB+64K
    //                     dinv@2MiB  xd@6MiB  hd@14MiB  pairs@18MiB (128MB)
    const size_t csr_need = 18 * MiB + (size_t)nE * 4;

    if (ws_size >= csr_need) {
        int*          hist  = (int*)ws;
        int*          bsum  = (int*)(ws + 1 * MiB);
        int*          flag  = (int*)(ws + 1 * MiB + 65536);
        float*        dinv  = (float*)(ws + 2 * MiB);
        float2*       xd    = (float2*)(ws + 6 * MiB);
        float*        hd    = (float*)(ws + 14 * MiB);
        unsigned int* pairs = (unsigned int*)(ws + 18 * MiB);

        detect_kernel<<<1, 256, 0, stream>>>(ei, flag);
        passA_kernel<<<GAB, 512, 0, stream>>>(ei, hist, flag, nE);
        scan1_kernel<<<NBS, SCAN_B, 0, stream>>>(hist, bsum, NL);
        scan2_kernel<<<1, 1024, 0, stream>>>(bsum, NBS);
        passC_kernel<<<GAB, CB, 0, stream>>>(ei, hist, bsum, pairs, flag, nE);
        passD0_kernel<<<NB, 1024, 0, stream>>>(pairs, hist, bsum, (const float2*)x,
                                               dinv, xd, nE, nN);
        passL1_kernel<<<NB, 1024, 0, stream>>>(pairs, hist, bsum, dinv, xd,
                                               W1, b1, W2, hd, nE, nN);
        passL2_kernel<<<NB, 1024, 0, stream>>>(pairs, hist, bsum, dinv, hd,
                                               b2, out, nE, nN);
    } else {
        // fallback layout: deg@0  agg@4..12  out2@12  dinv@16  xd@20..28  hd@28  flag@32MiB
        int*    deg  = (int*)ws;
        float*  agg  = (float*)(ws + 4 * MiB);
        float*  out2 = (float*)(ws + 12 * MiB);
        float*  dinv = (float*)(ws + 16 * MiB);
        float2* xd   = (float2*)(ws + 20 * MiB);
        float*  hd   = (float*)(ws + 28 * MiB);
        int*    flag = (int*)(ws + 32 * MiB);

        hipMemsetAsync(ws, 0, 16 * MiB, stream);

        detect_kernel<<<1, 256, 0, stream>>>(ei, flag);
        deg_kernel<<<(nE + bs - 1) / bs, bs, 0, stream>>>(ei, deg, flag, nE);
        prep_kernel<<<(nN + bs - 1) / bs, bs, 0, stream>>>(deg, (const float2*)x, dinv, xd, nN);
        l1a_kernel<<<(nE + bs - 1) / bs, bs, 0, stream>>>(ei, xd, agg, flag, nE);
        h2f_kernel<<<(nN + bs - 1) / bs, bs, 0, stream>>>((const float2*)agg, xd, dinv,
                                                          W1, b1, W2, hd, nN);
        l2a_kernel<<<(nE + bs - 1) / bs, bs, 0, stream>>>(ei, hd, out2, flag, nE);
        finf_kernel<<<(nN + bs - 1) / bs, bs, 0, stream>>>(out2, hd, dinv, b2, out, nN);
    }
}